// Round 1
// baseline (13142.041 us; speedup 1.0000x reference)
//
#include <hip/hip_runtime.h>
#include <hip/hip_bf16.h>
#include <stdint.h>

typedef __bf16 bf16;
typedef __bf16 bf16x8 __attribute__((ext_vector_type(8)));
typedef float floatx4 __attribute__((ext_vector_type(4)));

#define T_STEPS 512
#define BATCH   64
#define HID     1024
#define GN      3072      // 3 gates * HID
#define KDIM    1024
#define TB      (T_STEPS*BATCH)   // 32768
#define RPAD    1032      // padded LDS row stride (2064 B -> 2-way bank aliasing, free)

__device__ __forceinline__ float sigmoidf_(float x) {
  return 1.0f / (1.0f + __expf(-x));
}

// ---------------- small prep kernels ----------------

__global__ void cvt_f32_to_bf16(const float* __restrict__ src, bf16* __restrict__ dst, int n4) {
  int i = blockIdx.x * blockDim.x + threadIdx.x;
  if (i < n4) {
    float4 v = ((const float4*)src)[i];
    union { bf16 h[4]; uint2 u; } p;
    p.h[0] = (bf16)v.x; p.h[1] = (bf16)v.y; p.h[2] = (bf16)v.z; p.h[3] = (bf16)v.w;
    ((uint2*)dst)[i] = p.u;
  }
}

__global__ void combine_bias(const float* __restrict__ a, const float* __restrict__ b,
                             float* __restrict__ o, int n) {
  int i = blockIdx.x * blockDim.x + threadIdx.x;
  if (i < n) o[i] = a[i] + b[i];
}

__global__ void sigmoid_vec(const float* __restrict__ f, float* __restrict__ o, int n) {
  int i = blockIdx.x * blockDim.x + threadIdx.x;
  if (i < n) o[i] = sigmoidf_(f[i]);
}

__global__ void zero_words(uint32_t* __restrict__ p, int n) {
  int i = blockIdx.x * blockDim.x + threadIdx.x;
  if (i < n) p[i] = 0u;
}

// ---------------- big GEMM: C[M][3072] = A[M][1024] @ W[3072][1024]^T + bias ----------------
// 128x128 tile, 4 waves in 2x2, each wave 64x64 (4x4 MFMA 16x16x32 tiles), K-chunk 64.

__global__ __launch_bounds__(256) void gemm_nt_bias(
    const bf16* __restrict__ A,     // [M][1024] row-major
    const bf16* __restrict__ W,     // [3072][1024] row-major
    const float* __restrict__ bias, // [3072]
    bf16* __restrict__ C)           // [M][3072]
{
  __shared__ __align__(16) bf16 As[128][72];
  __shared__ __align__(16) bf16 Bs[128][72];
  const int tid  = threadIdx.x;
  const int lane = tid & 63;
  const int wave = tid >> 6;
  const int wm = (wave >> 1) * 64;
  const int wn = (wave & 1) * 64;
  const size_t m0 = (size_t)blockIdx.x * 128;
  const size_t n0 = (size_t)blockIdx.y * 128;
  const int fr = lane & 15, fk = (lane >> 4) * 8;

  floatx4 acc[4][4] = {};

  for (int k0 = 0; k0 < KDIM; k0 += 64) {
#pragma unroll
    for (int i = 0; i < 4; ++i) {
      int idx = tid + i * 256;
      int row = idx >> 3, seg = idx & 7;     // 8 x 16B per 64-elem row
      *(uint4*)&As[row][seg * 8] = *(const uint4*)(A + (m0 + row) * KDIM + k0 + seg * 8);
      *(uint4*)&Bs[row][seg * 8] = *(const uint4*)(W + (n0 + row) * KDIM + k0 + seg * 8);
    }
    __syncthreads();
#pragma unroll
    for (int ks = 0; ks < 2; ++ks) {
      bf16x8 af[4], bv[4];
#pragma unroll
      for (int i = 0; i < 4; ++i) af[i] = *(const bf16x8*)&As[wm + i * 16 + fr][ks * 32 + fk];
#pragma unroll
      for (int j = 0; j < 4; ++j) bv[j] = *(const bf16x8*)&Bs[wn + j * 16 + fr][ks * 32 + fk];
#pragma unroll
      for (int i = 0; i < 4; ++i)
#pragma unroll
        for (int j = 0; j < 4; ++j)
          acc[i][j] = __builtin_amdgcn_mfma_f32_16x16x32_bf16(af[i], bv[j], acc[i][j], 0, 0, 0);
    }
    __syncthreads();
  }

  const int col0 = lane & 15, row0 = (lane >> 4) * 4;
#pragma unroll
  for (int j = 0; j < 4; ++j) {
    const size_t n = n0 + wn + j * 16 + col0;
    const float bval = bias[n];
#pragma unroll
    for (int i = 0; i < 4; ++i) {
#pragma unroll
      for (int r = 0; r < 4; ++r) {
        const size_t m = m0 + wm + i * 16 + row0 + r;
        C[m * GN + n] = (bf16)(acc[i][j][r] + bval);
      }
    }
  }
}

// ---------------- persistent recurrent kernel ----------------
// 64 blocks (one per j-tile, 1 block/CU -> co-resident), 256 threads (4 waves).
// R-slice (48 rows x 1024) lives in LDS for all 512 steps; c-state lives in registers.
// h propagates through per-t global buffers; steps are synchronized with 4-way-split
// atomic arrival counters (release add after store drain, acquire polling).

__global__ __launch_bounds__(256) void sublstm_persist(
    const bf16* __restrict__ R,      // [3072][1024]
    const bf16* __restrict__ Gx,     // [512][64][3072]  x-projection + biases
    const float* __restrict__ fg,    // [1024] sigmoid(f)
    const bf16* __restrict__ h0,     // [64][1024] zeros (t=0 input)
    bf16* __restrict__ hout,         // [512][64][1024] bf16 h for next step / layer-1 GEMM
    float* __restrict__ fout,        // null, or [512][64][1024] f32 (layer-1 output)
    float* __restrict__ c_out,       // [64][1024] final c
    uint32_t* __restrict__ ctr)      // [512][64] (4 counters/step, stride 16 words)
{
  __shared__ __align__(16) bf16 Rs[48][RPAD];   // 99072 B
  const int tid  = threadIdx.x;
  const int lane = tid & 63;
  const int wave = tid >> 6;          // wave owns batch rows [wave*16, wave*16+16)
  const int jt   = blockIdx.x;        // 0..63
  const int fr = lane & 15, fk = (lane >> 4) * 8;

  // one-time: stage the 48 R rows (gates i/o/z at this j-tile) into LDS
#pragma unroll
  for (int i = 0; i < 24; ++i) {
    int idx = tid + i * 256;          // 0..6143
    int row = idx >> 7;               // 0..47
    int seg = idx & 127;              // 128 x 8 bf16 per row
    int g = row >> 4, jj = row & 15;
    const bf16* src = R + ((size_t)g * HID + jt * 16 + jj) * KDIM + seg * 8;
    *(uint4*)&Rs[row][seg * 8] = *(const uint4*)src;
  }

  const int j = jt * 16 + fr;
  const float fgj = fg[j];
  const int brow0 = wave * 16 + (lane >> 4) * 4;   // first of this thread's 4 batch rows
  float creg[4] = {0.f, 0.f, 0.f, 0.f};

  __syncthreads();

  const bf16* hprev = h0;
  for (int t = 0; t < T_STEPS; ++t) {
    // ---- prefetch Gx for the epilogue (independent of the flag wait) ----
    const bf16* gxt = Gx + (size_t)t * BATCH * GN;
    float gxi[4], gxo[4], gxz[4];
#pragma unroll
    for (int r = 0; r < 4; ++r) {
      const bf16* gx = gxt + (size_t)(brow0 + r) * GN + j;
      gxi[r] = (float)gx[0];
      gxo[r] = (float)gx[HID];
      gxz[r] = (float)gx[2 * HID];
    }

    // ---- wait until all 64 blocks published h_{t-1} ----
    if (t > 0) {
      if (tid == 0) {
        const uint32_t* c = ctr + (size_t)(t - 1) * 64;
        uint32_t s;
        do {
          s  = __hip_atomic_load(c +  0, __ATOMIC_ACQUIRE, __HIP_MEMORY_SCOPE_AGENT);
          s += __hip_atomic_load(c + 16, __ATOMIC_ACQUIRE, __HIP_MEMORY_SCOPE_AGENT);
          s += __hip_atomic_load(c + 32, __ATOMIC_ACQUIRE, __HIP_MEMORY_SCOPE_AGENT);
          s += __hip_atomic_load(c + 48, __ATOMIC_ACQUIRE, __HIP_MEMORY_SCOPE_AGENT);
          if (s < 64u) __builtin_amdgcn_s_sleep(1);
        } while (s < 64u);             // '<' is replay-safe (monotonic counters)
      }
      __syncthreads();
    }

    // ---- acc[g] = h_prev(16 rows) @ R_g(16 cols)^T over K=1024; A direct from global ----
    floatx4 acc0 = {0.f, 0.f, 0.f, 0.f}, acc1 = acc0, acc2 = acc0;
    const bf16* arow = hprev + (size_t)(wave * 16 + fr) * HID + fk;
    bf16x8 afA[4], afB[4];
#pragma unroll
    for (int ks = 0; ks < 4; ++ks) afA[ks] = *(const bf16x8*)(arow + ks * 32);
#pragma unroll
    for (int kp = 0; kp < 4; ++kp) {
      // prefetch odd chunk while computing even chunk
#pragma unroll
      for (int ks = 0; ks < 4; ++ks)
        afB[ks] = *(const bf16x8*)(arow + (2 * kp + 1) * 128 + ks * 32);
#pragma unroll
      for (int ks = 0; ks < 4; ++ks) {
        const int kk = (2 * kp) * 128 + ks * 32 + fk;
        bf16x8 b0 = *(const bf16x8*)&Rs[ 0 + fr][kk];
        bf16x8 b1 = *(const bf16x8*)&Rs[16 + fr][kk];
        bf16x8 b2 = *(const bf16x8*)&Rs[32 + fr][kk];
        acc0 = __builtin_amdgcn_mfma_f32_16x16x32_bf16(afA[ks], b0, acc0, 0, 0, 0);
        acc1 = __builtin_amdgcn_mfma_f32_16x16x32_bf16(afA[ks], b1, acc1, 0, 0, 0);
        acc2 = __builtin_amdgcn_mfma_f32_16x16x32_bf16(afA[ks], b2, acc2, 0, 0, 0);
      }
      if (kp < 3) {
#pragma unroll
        for (int ks = 0; ks < 4; ++ks)
          afA[ks] = *(const bf16x8*)(arow + (2 * kp + 2) * 128 + ks * 32);
      }
#pragma unroll
      for (int ks = 0; ks < 4; ++ks) {
        const int kk = (2 * kp + 1) * 128 + ks * 32 + fk;
        bf16x8 b0 = *(const bf16x8*)&Rs[ 0 + fr][kk];
        bf16x8 b1 = *(const bf16x8*)&Rs[16 + fr][kk];
        bf16x8 b2 = *(const bf16x8*)&Rs[32 + fr][kk];
        acc0 = __builtin_amdgcn_mfma_f32_16x16x32_bf16(afB[ks], b0, acc0, 0, 0, 0);
        acc1 = __builtin_amdgcn_mfma_f32_16x16x32_bf16(afB[ks], b1, acc1, 0, 0, 0);
        acc2 = __builtin_amdgcn_mfma_f32_16x16x32_bf16(afB[ks], b2, acc2, 0, 0, 0);
      }
    }

    // ---- epilogue: gates, cell update (c in registers), publish h ----
    bf16*  ho = hout + (size_t)t * BATCH * HID;
    float* fo = fout ? fout + (size_t)t * BATCH * HID : nullptr;
#pragma unroll
    for (int r = 0; r < 4; ++r) {
      float ig = sigmoidf_(acc0[r] + gxi[r]);
      float og = sigmoidf_(acc1[r] + gxo[r]);
      float zg = sigmoidf_(acc2[r] + gxz[r]);
      float c = creg[r] * fgj + zg - ig;
      creg[r] = c;
      float h = sigmoidf_(c) - og;
      size_t ci = (size_t)(brow0 + r) * HID + j;
      ho[ci] = (bf16)h;
      if (fo) fo[ci] = h;
    }
    __syncthreads();   // drains each thread's stores (vmcnt 0 before s_barrier)
    if (tid == 0)
      __hip_atomic_fetch_add(ctr + (size_t)t * 64 + (jt & 3) * 16, 1u,
                             __ATOMIC_RELEASE, __HIP_MEMORY_SCOPE_AGENT);
    hprev = ho;
  }

  // final c state for finalize
#pragma unroll
  for (int r = 0; r < 4; ++r)
    c_out[(size_t)(brow0 + r) * HID + j] = creg[r];
}

// ---------------- finalize: h_final[2][64][1024], c_final[2][64][1024] ----------------

__global__ void finalize_kernel(const bf16* __restrict__ h0_last,
                                const float* __restrict__ out_last,
                                const float* __restrict__ c0,
                                const float* __restrict__ c1,
                                float* __restrict__ dst) {
  int i = blockIdx.x * blockDim.x + threadIdx.x;   // 0..65535
  if (i < BATCH * HID) {
    dst[i]                      = (float)h0_last[i];  // h_final layer 0
    dst[BATCH * HID + i]        = out_last[i];        // h_final layer 1
    dst[2 * BATCH * HID + i]    = c0[i];              // c_final layer 0
    dst[3 * BATCH * HID + i]    = c1[i];              // c_final layer 1
  }
}

// ---------------- launch ----------------

extern "C" void kernel_launch(void* const* d_in, const int* in_sizes, int n_in,
                              void* d_out, int out_size, void* d_ws, size_t ws_size,
                              hipStream_t stream) {
  const float* x   = (const float*)d_in[0];
  const float* W0  = (const float*)d_in[1];
  const float* R0  = (const float*)d_in[2];
  const float* bi0 = (const float*)d_in[3];
  const float* bh0 = (const float*)d_in[4];
  const float* f0  = (const float*)d_in[5];
  const float* W1  = (const float*)d_in[6];
  const float* R1  = (const float*)d_in[7];
  const float* bi1 = (const float*)d_in[8];
  const float* bh1 = (const float*)d_in[9];
  const float* f1  = (const float*)d_in[10];
  float* out = (float*)d_out;

  char* ws = (char*)d_ws;
  size_t off = 0;
  auto alloc = [&](size_t bytes) {
    char* p = ws + off;
    off += (bytes + 255) & ~(size_t)255;
    return p;
  };
  bf16* W0b = (bf16*)alloc((size_t)GN * KDIM * 2);
  bf16* R0b = (bf16*)alloc((size_t)GN * KDIM * 2);
  bf16* W1b = (bf16*)alloc((size_t)GN * KDIM * 2);
  bf16* R1b = (bf16*)alloc((size_t)GN * KDIM * 2);
  bf16* xb  = (bf16*)alloc((size_t)TB * KDIM * 2);   // reused as layer-1 bf16 h after GEMM 0
  bf16* h0b = (bf16*)alloc((size_t)TB * HID * 2);
  bf16* Gx  = (bf16*)alloc((size_t)TB * GN * 2);
  float* b0c = (float*)alloc(GN * 4);
  float* b1c = (float*)alloc(GN * 4);
  float* fg0 = (float*)alloc(HID * 4);
  float* fg1 = (float*)alloc(HID * 4);
  float* c0s = (float*)alloc((size_t)BATCH * HID * 4);
  float* c1s = (float*)alloc((size_t)BATCH * HID * 4);
  // the next three must stay contiguous (zeroed in one kernel)
  bf16*     zb   = (bf16*)alloc((size_t)BATCH * HID * 2);          // 131072 B
  uint32_t* ctr0 = (uint32_t*)alloc((size_t)T_STEPS * 64 * 4);     // 131072 B
  uint32_t* ctr1 = (uint32_t*)alloc((size_t)T_STEPS * 64 * 4);     // 131072 B

  // --- prep ---
  {
    int n4 = GN * KDIM / 4;
    int blocks = (n4 + 255) / 256;
    cvt_f32_to_bf16<<<blocks, 256, 0, stream>>>(W0, W0b, n4);
    cvt_f32_to_bf16<<<blocks, 256, 0, stream>>>(R0, R0b, n4);
    cvt_f32_to_bf16<<<blocks, 256, 0, stream>>>(W1, W1b, n4);
    cvt_f32_to_bf16<<<blocks, 256, 0, stream>>>(R1, R1b, n4);
  }
  {
    int n4 = TB * KDIM / 4;
    cvt_f32_to_bf16<<<(n4 + 255) / 256, 256, 0, stream>>>(x, xb, n4);
  }
  combine_bias<<<(GN + 255) / 256, 256, 0, stream>>>(bi0, bh0, b0c, GN);
  combine_bias<<<(GN + 255) / 256, 256, 0, stream>>>(bi1, bh1, b1c, GN);
  sigmoid_vec<<<(HID + 255) / 256, 256, 0, stream>>>(f0, fg0, HID);
  sigmoid_vec<<<(HID + 255) / 256, 256, 0, stream>>>(f1, fg1, HID);
  {
    // zb + ctr0 + ctr1 (contiguous): zeroed every graph execution => replay-safe
    int nwords = (BATCH * HID * 2 + 2 * T_STEPS * 64 * 4) / 4;
    zero_words<<<(nwords + 255) / 256, 256, 0, stream>>>((uint32_t*)zb, nwords);
  }

  // --- layer 0: x-projection GEMM, then persistent recurrence ---
  gemm_nt_bias<<<dim3(TB / 128, GN / 128), 256, 0, stream>>>(xb, W0b, b0c, Gx);
  sublstm_persist<<<64, 256, 0, stream>>>(R0b, Gx, fg0, zb, h0b, nullptr, c0s, ctr0);

  // --- layer 1: h0-projection GEMM (frees xb), then persistent recurrence ---
  gemm_nt_bias<<<dim3(TB / 128, GN / 128), 256, 0, stream>>>(h0b, W1b, b1c, Gx);
  sublstm_persist<<<64, 256, 0, stream>>>(R1b, Gx, fg1, zb, xb, out, c1s, ctr1);

  // --- finals ---
  finalize_kernel<<<(BATCH * HID + 255) / 256, 256, 0, stream>>>(
      h0b + (size_t)(T_STEPS - 1) * BATCH * HID,
      out + (size_t)(T_STEPS - 1) * BATCH * HID,
      c0s, c1s,
      out + (size_t)T_STEPS * BATCH * HID);
}

// Round 2
// 9310.026 us; speedup vs baseline: 1.4116x; 1.4116x over previous
//
#include <hip/hip_runtime.h>
#include <hip/hip_bf16.h>
#include <stdint.h>

typedef __bf16 bf16;
typedef __bf16 bf16x8 __attribute__((ext_vector_type(8)));
typedef float floatx4 __attribute__((ext_vector_type(4)));

#define T_STEPS 512
#define BATCH   64
#define HID     1024
#define GN      3072      // 3 gates * HID
#define KDIM    1024
#define TB      (T_STEPS*BATCH)   // 32768
#define RPAD    1032      // padded LDS row stride (2064 B -> effective 2-way aliasing, free)

__device__ __forceinline__ float sigmoidf_(float x) {
  return 1.0f / (1.0f + __expf(-x));
}

// ---------------- small prep kernels ----------------

__global__ void cvt_f32_to_bf16(const float* __restrict__ src, bf16* __restrict__ dst, int n4) {
  int i = blockIdx.x * blockDim.x + threadIdx.x;
  if (i < n4) {
    float4 v = ((const float4*)src)[i];
    union { bf16 h[4]; uint2 u; } p;
    p.h[0] = (bf16)v.x; p.h[1] = (bf16)v.y; p.h[2] = (bf16)v.z; p.h[3] = (bf16)v.w;
    ((uint2*)dst)[i] = p.u;
  }
}

__global__ void combine_bias(const float* __restrict__ a, const float* __restrict__ b,
                             float* __restrict__ o, int n) {
  int i = blockIdx.x * blockDim.x + threadIdx.x;
  if (i < n) o[i] = a[i] + b[i];
}

__global__ void sigmoid_vec(const float* __restrict__ f, float* __restrict__ o, int n) {
  int i = blockIdx.x * blockDim.x + threadIdx.x;
  if (i < n) o[i] = sigmoidf_(f[i]);
}

__global__ void zero_words(uint32_t* __restrict__ p, int n) {
  int i = blockIdx.x * blockDim.x + threadIdx.x;
  if (i < n) p[i] = 0u;
}

// ---------------- big GEMM: C[M][3072] = A[M][1024] @ W[3072][1024]^T + bias ----------------
// 128x128 tile, 4 waves in 2x2, each wave 64x64 (4x4 MFMA 16x16x32 tiles), K-chunk 64.

__global__ __launch_bounds__(256) void gemm_nt_bias(
    const bf16* __restrict__ A,     // [M][1024] row-major
    const bf16* __restrict__ W,     // [3072][1024] row-major
    const float* __restrict__ bias, // [3072]
    bf16* __restrict__ C)           // [M][3072]
{
  __shared__ __align__(16) bf16 As[128][72];
  __shared__ __align__(16) bf16 Bs[128][72];
  const int tid  = threadIdx.x;
  const int lane = tid & 63;
  const int wave = tid >> 6;
  const int wm = (wave >> 1) * 64;
  const int wn = (wave & 1) * 64;
  const size_t m0 = (size_t)blockIdx.x * 128;
  const size_t n0 = (size_t)blockIdx.y * 128;
  const int fr = lane & 15, fk = (lane >> 4) * 8;

  floatx4 acc[4][4] = {};

  for (int k0 = 0; k0 < KDIM; k0 += 64) {
#pragma unroll
    for (int i = 0; i < 4; ++i) {
      int idx = tid + i * 256;
      int row = idx >> 3, seg = idx & 7;     // 8 x 16B per 64-elem row
      *(uint4*)&As[row][seg * 8] = *(const uint4*)(A + (m0 + row) * KDIM + k0 + seg * 8);
      *(uint4*)&Bs[row][seg * 8] = *(const uint4*)(W + (n0 + row) * KDIM + k0 + seg * 8);
    }
    __syncthreads();
#pragma unroll
    for (int ks = 0; ks < 2; ++ks) {
      bf16x8 af[4], bv[4];
#pragma unroll
      for (int i = 0; i < 4; ++i) af[i] = *(const bf16x8*)&As[wm + i * 16 + fr][ks * 32 + fk];
#pragma unroll
      for (int j = 0; j < 4; ++j) bv[j] = *(const bf16x8*)&Bs[wn + j * 16 + fr][ks * 32 + fk];
#pragma unroll
      for (int i = 0; i < 4; ++i)
#pragma unroll
        for (int j = 0; j < 4; ++j)
          acc[i][j] = __builtin_amdgcn_mfma_f32_16x16x32_bf16(af[i], bv[j], acc[i][j], 0, 0, 0);
    }
    __syncthreads();
  }

  const int col0 = lane & 15, row0 = (lane >> 4) * 4;
#pragma unroll
  for (int j = 0; j < 4; ++j) {
    const size_t n = n0 + wn + j * 16 + col0;
    const float bval = bias[n];
#pragma unroll
    for (int i = 0; i < 4; ++i) {
#pragma unroll
      for (int r = 0; r < 4; ++r) {
        const size_t m = m0 + wm + i * 16 + row0 + r;
        C[m * GN + n] = (bf16)(acc[i][j][r] + bval);
      }
    }
  }
}

// ---------------- persistent recurrent kernel ----------------
// 64 blocks (one per j-tile, 1 block/CU -> co-resident), 256 threads (4 waves).
// R-slice (48 rows x 1024) lives in LDS for all 512 steps; c-state lives in registers.
//
// Synchronization design (no cache-wide maintenance in the loop):
//  - h stores: per-access coherent (agent-scope RELAXED atomic 8B stores -> sc1
//    write-through to the coherence point). No buffer_wbl2.
//  - counter: RELAXED fetch_add AFTER __syncthreads (which drains vmcnt(0), i.e.
//    all h stores are acked/visible before the increment is issued).
//  - consumers: RELAXED polling loads (sc1, always fresh, no buffer_inv), then
//    PLAIN CACHED loads for h_prev. Safe because every h[t] address is written
//    exactly once per launch and only read after the counter says ready; the
//    launch-start invalidate removes any cross-replay residue. Cached h loads
//    let the 8 blocks of an XCD share h lines in L2.

__global__ __launch_bounds__(256) void sublstm_persist(
    const bf16* __restrict__ R,      // [3072][1024]
    const bf16* __restrict__ Gx,     // [512][64][3072]  x-projection + biases
    const float* __restrict__ fg,    // [1024] sigmoid(f)
    const bf16* __restrict__ h0,     // [64][1024] zeros (t=0 input)
    bf16* __restrict__ hout,         // [512][64][1024] bf16 h for next step / layer-1 GEMM
    float* __restrict__ fout,        // null, or [512][64][1024] f32 (layer-1 output)
    float* __restrict__ c_out,       // [64][1024] final c
    uint32_t* __restrict__ ctr)      // [512][128] (4 counters/step, stride 32 words = 128B)
{
  __shared__ __align__(16) bf16 Rs[48][RPAD];   // 99072 B
  __shared__ __align__(16) bf16 Ht[4][16][20];  // per-wave store-transpose tile (2560 B)
  const int tid  = threadIdx.x;
  const int lane = tid & 63;
  const int wave = tid >> 6;          // wave owns batch rows [wave*16, wave*16+16)
  // XCD swizzle: XCD k (bid%8) gets j-tiles [8k, 8k+8) -> the 4 j-tiles sharing
  // each 128B Gx line live on the same XCD L2.
  const int jt   = ((blockIdx.x & 7) << 3) | (blockIdx.x >> 3);
  const int fr = lane & 15, fk = (lane >> 4) * 8;

  // one-time: stage the 48 R rows (gates i/o/z at this j-tile) into LDS
#pragma unroll
  for (int i = 0; i < 24; ++i) {
    int idx = tid + i * 256;          // 0..6143
    int row = idx >> 7;               // 0..47
    int seg = idx & 127;              // 128 x 8 bf16 per row
    int g = row >> 4, jj = row & 15;
    const bf16* src = R + ((size_t)g * HID + jt * 16 + jj) * KDIM + seg * 8;
    *(uint4*)&Rs[row][seg * 8] = *(const uint4*)src;
  }

  const int j = jt * 16 + fr;
  const float fgj = fg[j];
  const int brow0 = wave * 16 + (lane >> 4) * 4;   // first of this thread's 4 batch rows
  float creg[4] = {0.f, 0.f, 0.f, 0.f};

  __syncthreads();

  const bf16* hprev = h0;
  for (int t = 0; t < T_STEPS; ++t) {
    // ---- prefetch Gx for the epilogue (issued before the flag wait) ----
    const bf16* gxt = Gx + (size_t)t * BATCH * GN;
    float gxi[4], gxo[4], gxz[4];
#pragma unroll
    for (int r = 0; r < 4; ++r) {
      const bf16* gx = gxt + (size_t)(brow0 + r) * GN + j;
      gxi[r] = (float)gx[0];
      gxo[r] = (float)gx[HID];
      gxz[r] = (float)gx[2 * HID];
    }

    // ---- wait until all 64 blocks published h_{t-1} (relaxed polls, no inv) ----
    if (t > 0) {
      if (tid == 0) {
        const uint32_t* c = ctr + (size_t)(t - 1) * 128;
        uint32_t s;
        do {
          s  = __hip_atomic_load(c +  0, __ATOMIC_RELAXED, __HIP_MEMORY_SCOPE_AGENT);
          s += __hip_atomic_load(c + 32, __ATOMIC_RELAXED, __HIP_MEMORY_SCOPE_AGENT);
          s += __hip_atomic_load(c + 64, __ATOMIC_RELAXED, __HIP_MEMORY_SCOPE_AGENT);
          s += __hip_atomic_load(c + 96, __ATOMIC_RELAXED, __HIP_MEMORY_SCOPE_AGENT);
          if (s < 64u) __builtin_amdgcn_s_sleep(2);
        } while (s < 64u);             // '<' is replay-safe (monotonic counters)
      }
      __syncthreads();                  // also a compiler barrier: h loads can't hoist
    }

    // ---- acc[g] = h_prev(16 rows) @ R_g(16 cols)^T over K=1024; A cached from global ----
    floatx4 acc0 = {0.f, 0.f, 0.f, 0.f}, acc1 = acc0, acc2 = acc0;
    const bf16* arow = hprev + (size_t)(wave * 16 + fr) * HID + fk;
    bf16x8 afA[4], afB[4];
#pragma unroll
    for (int ks = 0; ks < 4; ++ks) afA[ks] = *(const bf16x8*)(arow + ks * 32);
#pragma unroll
    for (int kp = 0; kp < 4; ++kp) {
      // prefetch odd chunk while computing even chunk
#pragma unroll
      for (int ks = 0; ks < 4; ++ks)
        afB[ks] = *(const bf16x8*)(arow + (2 * kp + 1) * 128 + ks * 32);
#pragma unroll
      for (int ks = 0; ks < 4; ++ks) {
        const int kk = (2 * kp) * 128 + ks * 32 + fk;
        bf16x8 b0 = *(const bf16x8*)&Rs[ 0 + fr][kk];
        bf16x8 b1 = *(const bf16x8*)&Rs[16 + fr][kk];
        bf16x8 b2 = *(const bf16x8*)&Rs[32 + fr][kk];
        acc0 = __builtin_amdgcn_mfma_f32_16x16x32_bf16(afA[ks], b0, acc0, 0, 0, 0);
        acc1 = __builtin_amdgcn_mfma_f32_16x16x32_bf16(afA[ks], b1, acc1, 0, 0, 0);
        acc2 = __builtin_amdgcn_mfma_f32_16x16x32_bf16(afA[ks], b2, acc2, 0, 0, 0);
      }
      if (kp < 3) {
#pragma unroll
        for (int ks = 0; ks < 4; ++ks)
          afA[ks] = *(const bf16x8*)(arow + (2 * kp + 2) * 128 + ks * 32);
      }
#pragma unroll
      for (int ks = 0; ks < 4; ++ks) {
        const int kk = (2 * kp + 1) * 128 + ks * 32 + fk;
        bf16x8 b0 = *(const bf16x8*)&Rs[ 0 + fr][kk];
        bf16x8 b1 = *(const bf16x8*)&Rs[16 + fr][kk];
        bf16x8 b2 = *(const bf16x8*)&Rs[32 + fr][kk];
        acc0 = __builtin_amdgcn_mfma_f32_16x16x32_bf16(afB[ks], b0, acc0, 0, 0, 0);
        acc1 = __builtin_amdgcn_mfma_f32_16x16x32_bf16(afB[ks], b1, acc1, 0, 0, 0);
        acc2 = __builtin_amdgcn_mfma_f32_16x16x32_bf16(afB[ks], b2, acc2, 0, 0, 0);
      }
    }

    // ---- epilogue: gates, cell update (c in registers), publish h coherently ----
    bf16*  ho = hout + (size_t)t * BATCH * HID;
    float* fo = fout ? fout + (size_t)t * BATCH * HID : nullptr;
#pragma unroll
    for (int r = 0; r < 4; ++r) {
      float ig = sigmoidf_(acc0[r] + gxi[r]);
      float og = sigmoidf_(acc1[r] + gxo[r]);
      float zg = sigmoidf_(acc2[r] + gxz[r]);
      float c = creg[r] * fgj + zg - ig;
      creg[r] = c;
      float h = sigmoidf_(c) - og;
      if (fo) fo[(size_t)(brow0 + r) * HID + j] = h;   // plain cached (read next kernel)
      Ht[wave][(lane >> 4) * 4 + r][fr] = (bf16)h;     // wave-local transpose tile
    }
    asm volatile("s_waitcnt lgkmcnt(0)" ::: "memory"); // wave-synchronous LDS transpose
    {
      const int rr = lane >> 2, cc = lane & 3;          // 16 rows x 4 chunks of 8B
      uint64_t v = *(const uint64_t*)&Ht[wave][rr][cc * 4];
      uint64_t* dst = (uint64_t*)(ho + (size_t)(wave * 16 + rr) * HID
                                     + (size_t)jt * 16 + cc * 4);
      __hip_atomic_store(dst, v, __ATOMIC_RELAXED, __HIP_MEMORY_SCOPE_AGENT);
    }
    __syncthreads();   // drains vmcnt(0): all coherent h stores acked before increment
    if (tid == 0)
      __hip_atomic_fetch_add(ctr + (size_t)t * 128 + (jt & 3) * 32, 1u,
                             __ATOMIC_RELAXED, __HIP_MEMORY_SCOPE_AGENT);
    hprev = ho;
  }

  // final c state for finalize
#pragma unroll
  for (int r = 0; r < 4; ++r)
    c_out[(size_t)(brow0 + r) * HID + j] = creg[r];
}

// ---------------- finalize: h_final[2][64][1024], c_final[2][64][1024] ----------------

__global__ void finalize_kernel(const bf16* __restrict__ h0_last,
                                const float* __restrict__ out_last,
                                const float* __restrict__ c0,
                                const float* __restrict__ c1,
                                float* __restrict__ dst) {
  int i = blockIdx.x * blockDim.x + threadIdx.x;   // 0..65535
  if (i < BATCH * HID) {
    dst[i]                      = (float)h0_last[i];  // h_final layer 0
    dst[BATCH * HID + i]        = out_last[i];        // h_final layer 1
    dst[2 * BATCH * HID + i]    = c0[i];              // c_final layer 0
    dst[3 * BATCH * HID + i]    = c1[i];              // c_final layer 1
  }
}

// ---------------- launch ----------------

extern "C" void kernel_launch(void* const* d_in, const int* in_sizes, int n_in,
                              void* d_out, int out_size, void* d_ws, size_t ws_size,
                              hipStream_t stream) {
  const float* x   = (const float*)d_in[0];
  const float* W0  = (const float*)d_in[1];
  const float* R0  = (const float*)d_in[2];
  const float* bi0 = (const float*)d_in[3];
  const float* bh0 = (const float*)d_in[4];
  const float* f0  = (const float*)d_in[5];
  const float* W1  = (const float*)d_in[6];
  const float* R1  = (const float*)d_in[7];
  const float* bi1 = (const float*)d_in[8];
  const float* bh1 = (const float*)d_in[9];
  const float* f1  = (const float*)d_in[10];
  float* out = (float*)d_out;

  char* ws = (char*)d_ws;
  size_t off = 0;
  auto alloc = [&](size_t bytes) {
    char* p = ws + off;
    off += (bytes + 255) & ~(size_t)255;
    return p;
  };
  bf16* W0b = (bf16*)alloc((size_t)GN * KDIM * 2);
  bf16* R0b = (bf16*)alloc((size_t)GN * KDIM * 2);
  bf16* W1b = (bf16*)alloc((size_t)GN * KDIM * 2);
  bf16* R1b = (bf16*)alloc((size_t)GN * KDIM * 2);
  bf16* xb  = (bf16*)alloc((size_t)TB * KDIM * 2);   // reused as layer-1 bf16 h after GEMM 0
  bf16* h0b = (bf16*)alloc((size_t)TB * HID * 2);
  bf16* Gx  = (bf16*)alloc((size_t)TB * GN * 2);
  float* b0c = (float*)alloc(GN * 4);
  float* b1c = (float*)alloc(GN * 4);
  float* fg0 = (float*)alloc(HID * 4);
  float* fg1 = (float*)alloc(HID * 4);
  float* c0s = (float*)alloc((size_t)BATCH * HID * 4);
  float* c1s = (float*)alloc((size_t)BATCH * HID * 4);
  // the next three must stay contiguous (zeroed in one kernel)
  bf16*     zb   = (bf16*)alloc((size_t)BATCH * HID * 2);           // 131072 B
  uint32_t* ctr0 = (uint32_t*)alloc((size_t)T_STEPS * 128 * 4);     // 262144 B
  uint32_t* ctr1 = (uint32_t*)alloc((size_t)T_STEPS * 128 * 4);     // 262144 B

  // --- prep ---
  {
    int n4 = GN * KDIM / 4;
    int blocks = (n4 + 255) / 256;
    cvt_f32_to_bf16<<<blocks, 256, 0, stream>>>(W0, W0b, n4);
    cvt_f32_to_bf16<<<blocks, 256, 0, stream>>>(R0, R0b, n4);
    cvt_f32_to_bf16<<<blocks, 256, 0, stream>>>(W1, W1b, n4);
    cvt_f32_to_bf16<<<blocks, 256, 0, stream>>>(R1, R1b, n4);
  }
  {
    int n4 = TB * KDIM / 4;
    cvt_f32_to_bf16<<<(n4 + 255) / 256, 256, 0, stream>>>(x, xb, n4);
  }
  combine_bias<<<(GN + 255) / 256, 256, 0, stream>>>(bi0, bh0, b0c, GN);
  combine_bias<<<(GN + 255) / 256, 256, 0, stream>>>(bi1, bh1, b1c, GN);
  sigmoid_vec<<<(HID + 255) / 256, 256, 0, stream>>>(f0, fg0, HID);
  sigmoid_vec<<<(HID + 255) / 256, 256, 0, stream>>>(f1, fg1, HID);
  {
    // zb + ctr0 + ctr1 (contiguous): zeroed every graph execution => replay-safe
    int nwords = (BATCH * HID * 2 + 2 * T_STEPS * 128 * 4) / 4;
    zero_words<<<(nwords + 255) / 256, 256, 0, stream>>>((uint32_t*)zb, nwords);
  }

  // --- layer 0: x-projection GEMM, then persistent recurrence ---
  gemm_nt_bias<<<dim3(TB / 128, GN / 128), 256, 0, stream>>>(xb, W0b, b0c, Gx);
  sublstm_persist<<<64, 256, 0, stream>>>(R0b, Gx, fg0, zb, h0b, nullptr, c0s, ctr0);

  // --- layer 1: h0-projection GEMM (frees xb), then persistent recurrence ---
  gemm_nt_bias<<<dim3(TB / 128, GN / 128), 256, 0, stream>>>(h0b, W1b, b1c, Gx);
  sublstm_persist<<<64, 256, 0, stream>>>(R1b, Gx, fg1, zb, xb, out, c1s, ctr1);

  // --- finals ---
  finalize_kernel<<<(BATCH * HID + 255) / 256, 256, 0, stream>>>(
      h0b + (size_t)(T_STEPS - 1) * BATCH * HID,
      out + (size_t)(T_STEPS - 1) * BATCH * HID,
      c0s, c1s,
      out + (size_t)T_STEPS * BATCH * HID);
}